// Round 17
// baseline (32.553 us; speedup 1.0000x reference)
//
#include <hip/hip_runtime.h>
#include <hip/hip_bf16.h>

#define B_SZ  64
#define N_SZ  512
#define K_SZ  16
#define EMB   128
#define R_TOT (B_SZ * N_SZ)   // 32768 rows

typedef __attribute__((ext_vector_type(8))) short bf16x8;
typedef __attribute__((ext_vector_type(4))) float f32x4;

// XOR-swizzled u16 index into a [*][128]-u16 LDS tile (16B-unit granularity).
#define SWZ(row, col) ((((row) << 7)) + ((((col) >> 3) ^ ((row) & 15)) << 3) + ((col) & 7))

static __device__ __forceinline__ unsigned short f2bf(float x) {
    __hip_bfloat16 h = __float2bfloat16(x);   // RNE
    return *reinterpret_cast<unsigned short*>(&h);
}
static __device__ __forceinline__ float bf_lo(unsigned int v) {
    union { unsigned int u; float f; } c; c.u = v << 16; return c.f;
}
static __device__ __forceinline__ float bf_hi(unsigned int v) {
    union { unsigned int u; float f; } c; c.u = v & 0xFFFF0000u; return c.f;
}

// W_enc [256][128] f32 -> wt[2][128][128] bf16, transposed: wt[half][e][f] = W_enc[half*128+f][e]
// (proven in R9: fragment = contiguous bf16x8 at wt[half*16384 + col*128 + ks*32 + g*8]).
// Also zeroes d_out (gather accumulates into it atomically).
__global__ __launch_bounds__(256) void prep_w(const float* __restrict__ W_enc,
                                              unsigned short* __restrict__ wt,
                                              float* __restrict__ out)
{
    __shared__ float s[16][128];
    const int tid = threadIdx.x;
    const int f0 = blockIdx.x * 16;          // 16 blocks cover 256 f-rows
    for (int i = tid; i < 2048; i += 256) {
        int r = i >> 7, c = i & 127;
        s[r][c] = W_enc[(f0 + r) * EMB + c];
    }
    for (int i = blockIdx.x * 256 + tid; i < B_SZ * EMB; i += 16 * 256) out[i] = 0.f;
    __syncthreads();
    if (tid < 128) {
        const int e = tid;
        unsigned short* dst = wt + ((f0 >= 128) ? (EMB * EMB) : 0) + e * EMB + (f0 & 127);
        for (int j = 0; j < 16; j += 2) {
            unsigned int v = (unsigned int)f2bf(s[j][e]) | ((unsigned int)f2bf(s[j + 1][e]) << 16);
            *(unsigned int*)(dst + j) = v;
        }
    }
}

// Fused: X = word@Wtop + bias (store bf16, pre-relu); Y = relu(X)@Wbot (store bf16).
// B-fragments load from pre-transposed wt as contiguous 16B bf16x8 (8 VMEM + 0 cvt
// per set, vs 128 scalar VMEM + 128 cvt from raw W_enc — the R11-probe issue bound).
// bfr2 loaded after the barrier (no prefetch); __launch_bounds__(256,4) for >=4 w/SIMD.
// XCD-affine block map: batch b's 8 row-blocks on XCD b&7 (matches gather).
__global__ __launch_bounds__(256, 4) void dual_gemm(const float* __restrict__ word,
                                                    const unsigned short* __restrict__ wt,
                                                    const float* __restrict__ bias,
                                                    unsigned short* __restrict__ Xb,
                                                    unsigned short* __restrict__ Yb)
{
    __shared__ unsigned short sA0[64 * EMB];   // 16 KB, bf16(word) tile, swizzled
    __shared__ unsigned short sA1[64 * EMB];   // 16 KB, relu(X) tile, swizzled
    const int tid = threadIdx.x;

    const int bid    = blockIdx.x;
    const int xcd    = bid & 7;
    const int j      = bid >> 3;
    const int b      = xcd + 8 * (j & 7);
    const int rchunk = j >> 3;
    const int block_row = b * N_SZ + rchunk * 64;

    for (int i = tid; i < 2048; i += 256) {          // A tile f32 -> bf16
        int r = i >> 5, c4 = i & 31;
        float4 v = ((const float4*)(word + (size_t)(block_row + r) * EMB))[c4];
        unsigned short o[4] = { f2bf(v.x), f2bf(v.y), f2bf(v.z), f2bf(v.w) };
        *(uint2*)&sA0[SWZ(r, c4 * 4)] = *(uint2*)o;
    }

    const int lane  = tid & 63;
    const int w     = tid >> 6;
    const int l15   = lane & 15;
    const int g     = lane >> 4;
    const int ncol0 = w * 32;

    // B fragments for GEMM1: contiguous 16B loads from wt (L2-hot, 64 KB total)
    bf16x8 bfr[2][4];
    #pragma unroll
    for (int nb = 0; nb < 2; ++nb)
        #pragma unroll
        for (int ks = 0; ks < 4; ++ks)
            bfr[nb][ks] = *(const bf16x8*)&wt[(size_t)(ncol0 + nb * 16 + l15) * EMB + ks * 32 + g * 8];

    f32x4 acc[4][2];
    #pragma unroll
    for (int mb = 0; mb < 4; ++mb)
        #pragma unroll
        for (int nb = 0; nb < 2; ++nb)
            acc[mb][nb] = (f32x4){0.f, 0.f, 0.f, 0.f};

    __syncthreads();   // sA0 staged

    // ---- GEMM1: sA0 @ Wtop ----
    #pragma unroll
    for (int ks = 0; ks < 4; ++ks) {
        bf16x8 a[4];
        #pragma unroll
        for (int mb = 0; mb < 4; ++mb)
            a[mb] = *(const bf16x8*)&sA0[SWZ(mb * 16 + l15, ks * 32 + g * 8)];
        #pragma unroll
        for (int mb = 0; mb < 4; ++mb)
            #pragma unroll
            for (int nb = 0; nb < 2; ++nb)
                acc[mb][nb] = __builtin_amdgcn_mfma_f32_16x16x32_bf16(a[mb], bfr[nb][ks], acc[mb][nb], 0, 0, 0);
    }

    // epilogue 1: X = acc + bias; store Xb (pre-relu); relu into sA1
    #pragma unroll
    for (int mb = 0; mb < 4; ++mb) {
        #pragma unroll
        for (int nb = 0; nb < 2; ++nb) {
            const int col = ncol0 + nb * 16 + l15;
            const float bv = bias[col];
            #pragma unroll
            for (int r = 0; r < 4; ++r) {
                const int row_l = mb * 16 + g * 4 + r;
                float x = acc[mb][nb][r] + bv;
                Xb[(size_t)(block_row + row_l) * EMB + col] = f2bf(x);
                sA1[SWZ(row_l, col)] = f2bf(fmaxf(x, 0.f));
            }
            acc[mb][nb] = (f32x4){0.f, 0.f, 0.f, 0.f};
        }
    }
    __syncthreads();   // sA1 complete

    // B fragments for GEMM2 (loaded here, not prefetched, to cut held VGPRs)
    bf16x8 bfr2[2][4];
    #pragma unroll
    for (int nb = 0; nb < 2; ++nb)
        #pragma unroll
        for (int ks = 0; ks < 4; ++ks)
            bfr2[nb][ks] = *(const bf16x8*)&wt[(size_t)EMB * EMB + (size_t)(ncol0 + nb * 16 + l15) * EMB + ks * 32 + g * 8];

    // ---- GEMM2: relu(X) @ Wbot ----
    #pragma unroll
    for (int ks = 0; ks < 4; ++ks) {
        bf16x8 a[4];
        #pragma unroll
        for (int mb = 0; mb < 4; ++mb)
            a[mb] = *(const bf16x8*)&sA1[SWZ(mb * 16 + l15, ks * 32 + g * 8)];
        #pragma unroll
        for (int mb = 0; mb < 4; ++mb)
            #pragma unroll
            for (int nb = 0; nb < 2; ++nb)
                acc[mb][nb] = __builtin_amdgcn_mfma_f32_16x16x32_bf16(a[mb], bfr2[nb][ks], acc[mb][nb], 0, 0, 0);
    }
    #pragma unroll
    for (int mb = 0; mb < 4; ++mb)
        #pragma unroll
        for (int nb = 0; nb < 2; ++nb) {
            const int col = ncol0 + nb * 16 + l15;
            #pragma unroll
            for (int r = 0; r < 4; ++r) {
                const int row_l = mb * 16 + g * 4 + r;
                Yb[(size_t)(block_row + row_l) * EMB + col] = f2bf(acc[mb][nb][r]);
            }
        }
}

// ==== gather: R16 structure (readlane index broadcast) + spread W2 epilogue ====
// Wave g: 8 n's; indices preloaded with 2 coalesced loads, extracted via readlane
// at compile-time positions. Epilogue: W2 product split across all 256 threads
// (thread t -> e = t&127, f-half = t>>7; 64 loads each), LDS-combined, then one
// atomicAdd per e. XCD map: batch b on XCD b&7.
__global__ __launch_bounds__(256) void gather_pool_w2(const unsigned short* __restrict__ Xb,
                                                      const unsigned short* __restrict__ Yb,
                                                      const int*   __restrict__ nbr,
                                                      const float* __restrict__ mask,
                                                      const float* __restrict__ W2,
                                                      float* __restrict__ out)
{
    const int bid   = blockIdx.x;
    const int xcd   = bid & 7;
    const int rest  = bid >> 3;
    const int chunk = rest & 15;
    const int b     = (rest >> 4) * 8 + xcd;
    const int g     = threadIdx.x >> 6;        // 4 waves
    const int lane  = threadIdx.x & 63;

    const unsigned int* Yw = (const unsigned int*)(Yb + (size_t)b * N_SZ * EMB); // uniform
    const unsigned int* Xw = (const unsigned int*)Xb;                            // uniform

    // wave-cooperative preload of this wave's 128 neighbor indices (2 VMEM total)
    const int* flat = nbr + ((size_t)b * N_SZ + chunk * 32 + g * 8) * K_SZ;
    const int c0 = flat[lane];         // n 0..3  (k-major: n*16+k)
    const int c1 = flat[64 + lane];    // n 4..7

    float s0 = 0.f, s1 = 0.f;
    #pragma unroll
    for (int nn = 0; nn < 8; ++nn) {
        const unsigned int base = (unsigned int)(b * N_SZ + chunk * 32 + g * 8 + nn);

        float a0a = 0.f, a0b = 0.f, a1a = 0.f, a1b = 0.f;
        #pragma unroll
        for (int k = 0; k < K_SZ; k += 2) {
            const int fp0 = nn * K_SZ + k;       // compile-time lane position
            const int fp1 = fp0 + 1;
            const int id0 = (fp0 < 64) ? __builtin_amdgcn_readlane(c0, fp0)
                                       : __builtin_amdgcn_readlane(c1, fp0 - 64);
            const int id1 = (fp1 < 64) ? __builtin_amdgcn_readlane(c0, fp1)
                                       : __builtin_amdgcn_readlane(c1, fp1 - 64);
            unsigned int v0 = Yw[(((unsigned int)id0) << 6) + lane];
            unsigned int v1 = Yw[(((unsigned int)id1) << 6) + lane];
            a0a += bf_lo(v0); a1a += bf_hi(v0);
            a0b += bf_lo(v1); a1b += bf_hi(v1);
        }
        unsigned int xv = Xw[(base << 6) + lane];
        const float m = mask[base];
        s0 += fmaxf(bf_lo(xv) + (a0a + a0b) * 0.0625f, 0.f) * m;
        s1 += fmaxf(bf_hi(xv) + (a1a + a1b) * 0.0625f, 0.f) * m;
    }

    // in-block reduce: 4 wave-partials -> chunk_pool[128] in sred[0][*]
    __shared__ float sred[4][EMB];
    const int e0 = lane * 2;
    sred[g][e0]     = s0;
    sred[g][e0 + 1] = s1;
    __syncthreads();
    const int t = threadIdx.x;
    if (t < EMB)
        sred[0][t] = sred[0][t] + sred[1][t] + sred[2][t] + sred[3][t];
    __syncthreads();

    // chunk_pool @ W2, split across all 256 threads: e = t&127, f-half = t>>7
    {
        const int e  = t & 127;
        const int fh = t >> 7;
        float r = 0.f;
        const float* w2p = W2 + (size_t)(fh * 64) * EMB + e;
        #pragma unroll 8
        for (int f = 0; f < 64; ++f) r += sred[0][fh * 64 + f] * w2p[(size_t)f * EMB];
        sred[2 + fh][e] = r;           // rows 2,3 free after the reduce barrier
    }
    __syncthreads();
    if (t < EMB)
        atomicAdd(&out[b * EMB + t], sred[2][t] + sred[3][t]);
}

extern "C" void kernel_launch(void* const* d_in, const int* in_sizes, int n_in,
                              void* d_out, int out_size, void* d_ws, size_t ws_size,
                              hipStream_t stream)
{
    const float* word  = (const float*)d_in[0];
    const int*   nbr   = (const int*)  d_in[1];
    const float* mask  = (const float*)d_in[2];
    const float* W_enc = (const float*)d_in[3];
    const float* b_enc = (const float*)d_in[4];
    const float* W2    = (const float*)d_in[5];
    float* out = (float*)d_out;

    unsigned short* wt = (unsigned short*)d_ws;          // [2][128][128] bf16, 64 KB
    unsigned short* Xb = wt + 2 * EMB * EMB;             // [32768][128] bf16, 8 MB
    unsigned short* Yb = Xb + (size_t)R_TOT * EMB;       // 8 MB

    prep_w        <<<16,         256, 0, stream>>>(W_enc, wt, out);
    dual_gemm     <<<R_TOT / 64, 256, 0, stream>>>(word, wt, b_enc, Xb, Yb);
    gather_pool_w2<<<B_SZ * 16,  256, 0, stream>>>(Xb, Yb, nbr, mask, W2, out);
}

// Round 18
// 30.655 us; speedup vs baseline: 1.0619x; 1.0619x over previous
//
#include <hip/hip_runtime.h>
#include <hip/hip_bf16.h>

#define B_SZ  64
#define N_SZ  512
#define K_SZ  16
#define EMB   128
#define R_TOT (B_SZ * N_SZ)   // 32768 rows

typedef __attribute__((ext_vector_type(8))) short bf16x8;
typedef __attribute__((ext_vector_type(4))) float f32x4;

// XOR-swizzled u16 index into a [*][128]-u16 LDS tile (16B-unit granularity).
#define SWZ(row, col) ((((row) << 7)) + ((((col) >> 3) ^ ((row) & 15)) << 3) + ((col) & 7))

static __device__ __forceinline__ unsigned short f2bf(float x) {
    __hip_bfloat16 h = __float2bfloat16(x);   // RNE
    return *reinterpret_cast<unsigned short*>(&h);
}
static __device__ __forceinline__ float bf_lo(unsigned int v) {
    union { unsigned int u; float f; } c; c.u = v << 16; return c.f;
}
static __device__ __forceinline__ float bf_hi(unsigned int v) {
    union { unsigned int u; float f; } c; c.u = v & 0xFFFF0000u; return c.f;
}

// ==== dual_gemm: exact R12/R16 version (best measured) ====
// X = word@Wtop + bias (store bf16, pre-relu); Y = relu(X)@Wbot (store bf16).
// B-fragments direct from W_enc (coalesced scalar loads, L2-hot); bfr2 loaded
// after the barrier to cut held VGPRs; __launch_bounds__(256,3) -> 3 waves/SIMD.
// First 32 blocks zero d_out. XCD-affine map: batch b's blocks on XCD b&7.
__global__ __launch_bounds__(256, 3) void dual_gemm(const float* __restrict__ word,
                                                    const float* __restrict__ W_enc,
                                                    const float* __restrict__ bias,
                                                    unsigned short* __restrict__ Xb,
                                                    unsigned short* __restrict__ Yb,
                                                    float* __restrict__ out)
{
    __shared__ unsigned short sA0[64 * EMB];   // 16 KB, bf16(word) tile, swizzled
    __shared__ unsigned short sA1[64 * EMB];   // 16 KB, relu(X) tile, swizzled
    const int tid = threadIdx.x;

    const int bid    = blockIdx.x;
    const int xcd    = bid & 7;
    const int j      = bid >> 3;
    const int b      = xcd + 8 * (j & 7);
    const int rchunk = j >> 3;
    const int block_row = b * N_SZ + rchunk * 64;

    if (bid < 32) out[bid * 256 + tid] = 0.f;

    for (int i = tid; i < 2048; i += 256) {
        int r = i >> 5, c4 = i & 31;
        float4 v = ((const float4*)(word + (size_t)(block_row + r) * EMB))[c4];
        unsigned short o[4] = { f2bf(v.x), f2bf(v.y), f2bf(v.z), f2bf(v.w) };
        *(uint2*)&sA0[SWZ(r, c4 * 4)] = *(uint2*)o;
    }

    const int lane  = tid & 63;
    const int w     = tid >> 6;
    const int l15   = lane & 15;
    const int g     = lane >> 4;
    const int ncol0 = w * 32;

    bf16x8 bfr[2][4];
    #pragma unroll
    for (int nb = 0; nb < 2; ++nb) {
        const int col = ncol0 + nb * 16 + l15;
        #pragma unroll
        for (int ks = 0; ks < 4; ++ks) {
            unsigned short t[8];
            #pragma unroll
            for (int jj = 0; jj < 8; ++jj)
                t[jj] = f2bf(W_enc[(size_t)(ks * 32 + g * 8 + jj) * EMB + col]);
            bfr[nb][ks] = *(bf16x8*)t;
        }
    }

    f32x4 acc[4][2];
    #pragma unroll
    for (int mb = 0; mb < 4; ++mb)
        #pragma unroll
        for (int nb = 0; nb < 2; ++nb)
            acc[mb][nb] = (f32x4){0.f, 0.f, 0.f, 0.f};

    __syncthreads();

    // ---- GEMM1: sA0 @ Wtop ----
    #pragma unroll
    for (int ks = 0; ks < 4; ++ks) {
        bf16x8 a[4];
        #pragma unroll
        for (int mb = 0; mb < 4; ++mb)
            a[mb] = *(const bf16x8*)&sA0[SWZ(mb * 16 + l15, ks * 32 + g * 8)];
        #pragma unroll
        for (int mb = 0; mb < 4; ++mb)
            #pragma unroll
            for (int nb = 0; nb < 2; ++nb)
                acc[mb][nb] = __builtin_amdgcn_mfma_f32_16x16x32_bf16(a[mb], bfr[nb][ks], acc[mb][nb], 0, 0, 0);
    }

    // epilogue 1: X = acc + bias; store Xb (pre-relu); relu into sA1
    #pragma unroll
    for (int mb = 0; mb < 4; ++mb) {
        #pragma unroll
        for (int nb = 0; nb < 2; ++nb) {
            const int col = ncol0 + nb * 16 + l15;
            const float bv = bias[col];
            #pragma unroll
            for (int r = 0; r < 4; ++r) {
                const int row_l = mb * 16 + g * 4 + r;
                float x = acc[mb][nb][r] + bv;
                Xb[(size_t)(block_row + row_l) * EMB + col] = f2bf(x);
                sA1[SWZ(row_l, col)] = f2bf(fmaxf(x, 0.f));
            }
            acc[mb][nb] = (f32x4){0.f, 0.f, 0.f, 0.f};
        }
    }
    __syncthreads();

    // B fragments for GEMM2 (Wbot, L2-hot) — loaded here to cut VGPR
    bf16x8 bfr2[2][4];
    #pragma unroll
    for (int nb = 0; nb < 2; ++nb) {
        const int col = ncol0 + nb * 16 + l15;
        #pragma unroll
        for (int ks = 0; ks < 4; ++ks) {
            unsigned short t[8];
            #pragma unroll
            for (int jj = 0; jj < 8; ++jj)
                t[jj] = f2bf(W_enc[(size_t)(128 + ks * 32 + g * 8 + jj) * EMB + col]);
            bfr2[nb][ks] = *(bf16x8*)t;
        }
    }

    // ---- GEMM2: relu(X) @ Wbot ----
    #pragma unroll
    for (int ks = 0; ks < 4; ++ks) {
        bf16x8 a[4];
        #pragma unroll
        for (int mb = 0; mb < 4; ++mb)
            a[mb] = *(const bf16x8*)&sA1[SWZ(mb * 16 + l15, ks * 32 + g * 8)];
        #pragma unroll
        for (int mb = 0; mb < 4; ++mb)
            #pragma unroll
            for (int nb = 0; nb < 2; ++nb)
                acc[mb][nb] = __builtin_amdgcn_mfma_f32_16x16x32_bf16(a[mb], bfr2[nb][ks], acc[mb][nb], 0, 0, 0);
    }
    #pragma unroll
    for (int mb = 0; mb < 4; ++mb)
        #pragma unroll
        for (int nb = 0; nb < 2; ++nb) {
            const int col = ncol0 + nb * 16 + l15;
            #pragma unroll
            for (int r = 0; r < 4; ++r) {
                const int row_l = mb * 16 + g * 4 + r;
                Yb[(size_t)(block_row + row_l) * EMB + col] = f2bf(acc[mb][nb][r]);
            }
        }
}

// ==== gather: R16 version — readlane index broadcast ====
// Each wave's 8 n x 16 k = 128 neighbor indices preloaded by TWO coalesced
// per-lane loads, extracted via v_readlane at compile-time lane positions ->
// SGPR indices, scalar-pipe Y-row address math. In-block reduce ->
// chunk_pool[128] -> @W2 -> atomicAdd into out[b]. Batch b on XCD b&7.
__global__ __launch_bounds__(256) void gather_pool_w2(const unsigned short* __restrict__ Xb,
                                                      const unsigned short* __restrict__ Yb,
                                                      const int*   __restrict__ nbr,
                                                      const float* __restrict__ mask,
                                                      const float* __restrict__ W2,
                                                      float* __restrict__ out)
{
    const int bid   = blockIdx.x;
    const int xcd   = bid & 7;
    const int rest  = bid >> 3;
    const int chunk = rest & 15;
    const int b     = (rest >> 4) * 8 + xcd;
    const int g     = threadIdx.x >> 6;        // 4 waves
    const int lane  = threadIdx.x & 63;

    const unsigned int* Yw = (const unsigned int*)(Yb + (size_t)b * N_SZ * EMB); // uniform
    const unsigned int* Xw = (const unsigned int*)Xb;                            // uniform

    // wave-cooperative preload of this wave's 128 neighbor indices (2 VMEM total)
    const int* flat = nbr + ((size_t)b * N_SZ + chunk * 32 + g * 8) * K_SZ;
    const int c0 = flat[lane];         // n 0..3  (k-major: n*16+k)
    const int c1 = flat[64 + lane];    // n 4..7

    float s0 = 0.f, s1 = 0.f;
    #pragma unroll
    for (int nn = 0; nn < 8; ++nn) {
        const unsigned int base = (unsigned int)(b * N_SZ + chunk * 32 + g * 8 + nn);

        float a0a = 0.f, a0b = 0.f, a1a = 0.f, a1b = 0.f;
        #pragma unroll
        for (int k = 0; k < K_SZ; k += 2) {
            const int fp0 = nn * K_SZ + k;       // compile-time lane position
            const int fp1 = fp0 + 1;
            const int id0 = (fp0 < 64) ? __builtin_amdgcn_readlane(c0, fp0)
                                       : __builtin_amdgcn_readlane(c1, fp0 - 64);
            const int id1 = (fp1 < 64) ? __builtin_amdgcn_readlane(c0, fp1)
                                       : __builtin_amdgcn_readlane(c1, fp1 - 64);
            unsigned int v0 = Yw[(((unsigned int)id0) << 6) + lane];
            unsigned int v1 = Yw[(((unsigned int)id1) << 6) + lane];
            a0a += bf_lo(v0); a1a += bf_hi(v0);
            a0b += bf_lo(v1); a1b += bf_hi(v1);
        }
        unsigned int xv = Xw[(base << 6) + lane];
        const float m = mask[base];
        s0 += fmaxf(bf_lo(xv) + (a0a + a0b) * 0.0625f, 0.f) * m;
        s1 += fmaxf(bf_hi(xv) + (a1a + a1b) * 0.0625f, 0.f) * m;
    }

    // in-block reduce: 4 wave-partials -> chunk_pool[128] in sred[0][*]
    __shared__ float sred[4][EMB];
    const int e0 = lane * 2;
    sred[g][e0]     = s0;
    sred[g][e0 + 1] = s1;
    __syncthreads();
    const int t = threadIdx.x;
    if (t < EMB)
        sred[0][t] = sred[0][t] + sred[1][t] + sred[2][t] + sred[3][t];
    __syncthreads();

    // chunk_pool @ W2 -> atomicAdd into out[b][*]
    if (t < EMB) {
        float r = 0.f;
        #pragma unroll 8
        for (int f = 0; f < EMB; ++f) r += sred[0][f] * W2[f * EMB + t];
        atomicAdd(&out[b * EMB + t], r);
    }
}

extern "C" void kernel_launch(void* const* d_in, const int* in_sizes, int n_in,
                              void* d_out, int out_size, void* d_ws, size_t ws_size,
                              hipStream_t stream)
{
    const float* word  = (const float*)d_in[0];
    const int*   nbr   = (const int*)  d_in[1];
    const float* mask  = (const float*)d_in[2];
    const float* W_enc = (const float*)d_in[3];
    const float* b_enc = (const float*)d_in[4];
    const float* W2    = (const float*)d_in[5];
    float* out = (float*)d_out;

    unsigned short* Xb = (unsigned short*)d_ws;          // [32768][128] bf16, 8 MB
    unsigned short* Yb = Xb + (size_t)R_TOT * EMB;       // 8 MB

    dual_gemm     <<<R_TOT / 64, 256, 0, stream>>>(word, W_enc, b_enc, Xb, Yb, out);
    gather_pool_w2<<<B_SZ * 16,  256, 0, stream>>>(Xb, Yb, nbr, mask, W2, out);
}